// Round 7
// baseline (1221.645 us; speedup 1.0000x reference)
//
#include <hip/hip_runtime.h>
#include <math.h>
#include <stdint.h>

#define Lr 32
#define Hh 128
#define NCELL (Lr * Lr)
#define NEPS 1e-8f
#define CELLB 33792            // 32KB A-fragment image + 1KB candidate tail
#define ELEMS 16               // batch elements per block (= MFMA N)

typedef _Float16 f16;
typedef f16 f16x4 __attribute__((ext_vector_type(4)));
typedef f16 f16x8 __attribute__((ext_vector_type(8)));
typedef float f32x4 __attribute__((ext_vector_type(4)));
typedef uint32_t u32;
typedef u32 u32x2 __attribute__((ext_vector_type(2)));
typedef u32 u32x4 __attribute__((ext_vector_type(4)));

// LDS-publish barrier (does NOT touch vmcnt: in-flight weight loads survive).
__device__ __forceinline__ void bar_lds() {
    asm volatile("s_waitcnt lgkmcnt(0)\n\ts_barrier" ::: "memory");
}

__device__ __forceinline__ f16x8 asf16x8(u32x4 v) {
    union { u32x4 u; f16x8 h; } c; c.u = v; return c.h;
}
__device__ __forceinline__ float h16(u32 wd, int hi) {
    union { unsigned short u; f16 h; } c;
    c.u = (unsigned short)(hi ? (wd >> 16) : (wd & 0xffff));
    return (float)c.h;
}
__device__ __forceinline__ float fast_tanh(float x) {
    x = fminf(9.f, fmaxf(-9.f, x));
    const float e = __expf(2.f * x);
    return 1.f - 2.f / (e + 1.f);
}
__device__ __forceinline__ int cell_of(int s) {
    const int i = s >> 5, jj = s & 31;
    const int c = (i & 1) ? (Lr - 1 - jj) : jj;
    return i * Lr + c;
}

// W1[cell][k][m] (fp32, k<128, m: 0,1=spin cols, 2..129=h cols) -> 33KB image:
//  A-frag region (32KB): entry (kw<4, mt<8, lane<64) = 16B = 8 f16:
//    A[row = mt*16 + (lane&15)][kh = kw*32 + (lane>>4)*8 + j], j=0..7
//    (the v_mfma_f32_16x16x32_f16 A-fragment each lane loads directly;
//     wave mt reads 4x coalesced 1KB dwordx4 per cell).
//  tail (1KB): per k: 8B f16 {t0,t1,t2,wf}; binary spins fold spin-cols+bias:
//    t0=2W[k][1]+2b, t1=W[k][0]+W[k][1]+2b, t2=2W[k][0]+2b.
__global__ __launch_bounds__(256)
void transpose_w(const float* __restrict__ W1, const float* __restrict__ b1,
                 const float* __restrict__ Wf, char* __restrict__ Wt) {
    __shared__ float tile[Hh * 130];    // 66.6 KB
    const int cell = blockIdx.x;
    const float* src = W1 + (size_t)cell * (Hh * 130);
    for (int idx = threadIdx.x; idx < Hh * 130; idx += 256) tile[idx] = src[idx];
    __syncthreads();
    char* dst = Wt + (size_t)cell * CELLB;
    for (int idx = threadIdx.x; idx < 2048; idx += 256) {
        const int kw = idx >> 9, mt = (idx >> 6) & 7, l = idx & 63;
        const int row = mt * 16 + (l & 15);
        const int k0 = kw * 32 + (l >> 4) * 8;
        union { u32x4 v; f16 h[8]; } o;
        for (int j = 0; j < 8; ++j) o.h[j] = (f16)tile[row * 130 + 2 + k0 + j];
        *(u32x4*)(dst + idx * 16) = o.v;
    }
    if (threadIdx.x < Hh) {
        const int kk = threadIdx.x;
        union { u32x2 v; f16 h[4]; } o;
        const float w0 = tile[kk * 130 + 0], w1 = tile[kk * 130 + 1];
        const float bb = 2.f * b1[cell * Hh + kk];
        o.h[0] = (f16)(2.f * w1 + bb);
        o.h[1] = (f16)(w0 + w1 + bb);
        o.h[2] = (f16)(2.f * w0 + bb);
        o.h[3] = (f16)Wf[cell * Hh + kk];
        *(u32x2*)(dst + 32768 + kk * 8) = o.v;
    }
}

// 32 blocks x 16 batch elements, 512 threads (8 waves), 1 block/CU.
// Per cell: D(128x16) = W(128x130) . X(130x16) via 8 M-tiles of
// v_mfma_f32_16x16x32_f16 (wave w owns M-tile w: 4 MFMA + epilogue).
// All per-cell scaffolding (tanh/head/state) serves 16 elements at once
// (round 6 showed >90% of VALU issue was per-element scaffolding).
// Lane roles: e = t&15 (element / MFMA col), g = (t>>4)&3, own D rows
// k = w*16 + g*4 + {0..3}. Weights: asm-volatile register prefetch,
// 4 rotating buffers, counted vmcnt(12). One LDS barrier per cell.
__global__ __launch_bounds__(512, 2)
void rnn2d(const float* __restrict__ samples,
           const char* __restrict__ Wt,
           const float* __restrict__ bfv,
           float* __restrict__ out)
{
    __shared__ __align__(16) f16 hvl[512 * 132];        // 132 KB h_v, per-LANE slab:
                                                        // lane t owns [t*132 + col*4 .. +3]
                                                        // (writer==reader lane: race-free,
                                                        //  stride 264B -> conflict-free b64)
    __shared__ __align__(16) f16 inpL[2][ELEMS * 136];  // X dbuf, [e][kh], 136-pad banks
    __shared__ u32   smpw[NCELL];                       // spin bitmask, bit e
    __shared__ float bfs[NCELL];
    __shared__ __align__(16) float fp_[2][ELEMS][8];    // head partials [par][e][wave]

    const int t  = threadIdx.x;
    const int l  = t & 63;
    const int w  = t >> 6;            // wave = M-tile
    const int e  = t & 15;            // element (B/D column)
    const int g  = (t >> 4) & 3;      // k-group within wave
    const int b0 = blockIdx.x * ELEMS;

    // loop-invariant global byte offsets
    const u32 vc0 = (u32)(((0 * 8 + w) * 64 + l) * 16);
    const u32 vc1 = (u32)(((1 * 8 + w) * 64 + l) * 16);
    const u32 vc2 = (u32)(((2 * 8 + w) * 64 + l) * 16);
    const u32 vc3 = (u32)(((3 * 8 + w) * 64 + l) * 16);
    const u32 kq  = (u32)(w * 16 + g * 4);        // own D-row quad base
    const u32 vt0 = 32768 + kq * 8, vt1 = vt0 + 16;

    {   // init: h_v slab, X buffers, head partials, spin bitmask, bias
        for (int c = 0; c < 33; ++c) *(f16x4*)&hvl[t * 132 + c * 4] = (f16x4)0;
        u32* z = (u32*)inpL;
        for (int idx = t; idx < 2176; idx += 512) z[idx] = 0;
        if (t < 256) ((u32*)fp_)[t] = 0;
        u32 w0 = 0, w1 = 0;
        for (int ee = 0; ee < ELEMS; ++ee) {
            w0 |= (samples[(size_t)(b0 + ee) * NCELL + t] != 0.f ? 1u : 0u) << ee;
            w1 |= (samples[(size_t)(b0 + ee) * NCELL + t + 512] != 0.f ? 1u : 0u) << ee;
        }
        smpw[t] = w0; smpw[t + 512] = w1;
        bfs[t] = bfv[t]; bfs[t + 512] = bfv[t + 512];
    }
    float lp = 0.f;
    __syncthreads();

    u32x4 A0,A1,A2,A3, B0,B1,B2,B3, C0,C1,C2,C3, D0,D1,D2,D3;
    u32x4 AT0,AT1, BT0,BT1, CT0,CT1, DT0,DT1;

// 6 uniform volatile loads for cell S into one register buffer (un-sinkable)
#define ISSUE(S, R0,R1,R2,R3, T0,T1)                                        \
    {                                                                       \
        const int s_ = ((S) < NCELL) ? (S) : 0;                             \
        const char* cb_ = Wt + (size_t)cell_of(s_) * CELLB;                 \
        asm volatile("global_load_dwordx4 %0, %1, %2" : "=v"(R0) : "v"(vc0), "s"(cb_)); \
        asm volatile("global_load_dwordx4 %0, %1, %2" : "=v"(R1) : "v"(vc1), "s"(cb_)); \
        asm volatile("global_load_dwordx4 %0, %1, %2" : "=v"(R2) : "v"(vc2), "s"(cb_)); \
        asm volatile("global_load_dwordx4 %0, %1, %2" : "=v"(R3) : "v"(vc3), "s"(cb_)); \
        asm volatile("global_load_dwordx4 %0, %1, %2" : "=v"(T0) : "v"(vt0), "s"(cb_)); \
        asm volatile("global_load_dwordx4 %0, %1, %2" : "=v"(T1) : "v"(vt1), "s"(cb_)); \
    }

// counted wait: retire all but the newest 2 stages (2 x 6 loads)
#define WAITP()                                                             \
    asm volatile("s_waitcnt vmcnt(12)" ::: "memory");                       \
    __builtin_amdgcn_sched_barrier(0);

#define PROC(S, Q, R0,R1,R2,R3, T0,T1)                                      \
    {                                                                       \
        const int i_ = (S) >> 5, j_ = (S) & 31;                             \
        const int c_ = (i_ & 1) ? (Lr - 1 - j_) : j_;                       \
        const int sn_ = ((S) + 1 < NCELL) ? (S) + 1 : (S);                  \
        const int in_ = sn_ >> 5, jn_ = sn_ & 31;                           \
        const int cn_ = (in_ & 1) ? (Lr - 1 - jn_) : jn_;                   \
        /* own-lane h_v for next cell's column (race-free private slab) */  \
        const f16x4 hvp = *(const f16x4*)&hvl[t * 132 + cn_ * 4];           \
        /* deferred log-prob for cell S-1: wave 0, lanes 0..31 (2 halves) */\
        if (w == 0 && l < 32 && (S) > 0) {                                  \
            const int hf_ = l >> 4;                                         \
            const int cp_ = cell_of((S) - 1);                               \
            const float4 fa_ = *(const float4*)&fp_[Q][e][0];               \
            const float4 fb_ = *(const float4*)&fp_[Q][e][4];               \
            const float z_ = ((fa_.x + fa_.y) + (fa_.z + fa_.w))            \
                           + ((fb_.x + fb_.y) + (fb_.z + fb_.w)) + bfs[cp_];\
            const float xh_ = 1.f / (1.f + __expf(-z_));                    \
            const float m_ = (float)((smpw[cp_] >> e) & 1);                 \
            lp += (hf_ == 0) ? __logf(xh_ + NEPS) * m_                      \
                             : __logf(1.f - xh_ + NEPS) * (1.f - m_);       \
        }                                                                   \
        /* per-element spin case (binary spins) + candidate select */       \
        const int spv_ = (j_ > 0) ? cell_of((S)-1 >= 0 ? (S)-1 : 0) : 0;    \
        const u32 wh_ = (j_ > 0) ? smpw[spv_] : 0u;                         \
        const u32 wv_ = (i_ > 0) ? smpw[(i_ - 1) * Lr + c_] : 0u;           \
        const int cse = (int)((wh_ >> e) & 1) + (int)((wv_ >> e) & 1);      \
        const u32 q0l = T0.x, q0h = T0.y, q1l = T0.z, q1h = T0.w;           \
        const u32 q2l = T1.x, q2h = T1.y, q3l = T1.z, q3h = T1.w;           \
        const float ts0 = (cse==0)?h16(q0l,0):((cse==1)?h16(q0l,1):h16(q0h,0)); \
        const float ts1 = (cse==0)?h16(q1l,0):((cse==1)?h16(q1l,1):h16(q1h,0)); \
        const float ts2 = (cse==0)?h16(q2l,0):((cse==1)?h16(q2l,1):h16(q2h,0)); \
        const float ts3 = (cse==0)?h16(q3l,0):((cse==1)?h16(q3l,1):h16(q3h,0)); \
        /* B-fragments: 8 consecutive kh for own (e, g) — 16B LDS reads */  \
        const f16* ib_ = &inpL[Q][e * 136];                                 \
        const f16x8 bq0 = *(const f16x8*)(ib_ +  0 + g * 8);                \
        const f16x8 bq1 = *(const f16x8*)(ib_ + 32 + g * 8);                \
        const f16x8 bq2 = *(const f16x8*)(ib_ + 64 + g * 8);                \
        const f16x8 bq3 = *(const f16x8*)(ib_ + 96 + g * 8);                \
        f32x4 accA; accA[0]=ts0; accA[1]=ts1; accA[2]=ts2; accA[3]=ts3;     \
        f32x4 accB = (f32x4)0.f;                                            \
        accA = __builtin_amdgcn_mfma_f32_16x16x32_f16(asf16x8(R0), bq0, accA, 0,0,0); \
        accB = __builtin_amdgcn_mfma_f32_16x16x32_f16(asf16x8(R2), bq2, accB, 0,0,0); \
        accA = __builtin_amdgcn_mfma_f32_16x16x32_f16(asf16x8(R1), bq1, accA, 0,0,0); \
        accB = __builtin_amdgcn_mfma_f32_16x16x32_f16(asf16x8(R3), bq3, accB, 0,0,0); \
        const f32x4 acc = accA + accB;                                      \
        const float h0 = fast_tanh(acc[0]);                                 \
        const float h1 = fast_tanh(acc[1]);                                 \
        const float h2 = fast_tanh(acc[2]);                                 \
        const float h3 = fast_tanh(acc[3]);                                 \
        /* head partial: own 4 rows x wf, reduce over g via 2 shfl_xor */   \
        float f_ = h0 * h16(q0h,1);                                         \
        f_ = fmaf(h1, h16(q1h,1), f_);                                      \
        f_ = fmaf(h2, h16(q2h,1), f_);                                      \
        f_ = fmaf(h3, h16(q3h,1), f_);                                      \
        f_ += __shfl_xor(f_, 16);                                           \
        f_ += __shfl_xor(f_, 32);                                           \
        if (l < 16) fp_[(Q) ^ 1][e][w] = f_;                                \
        /* next-cell X entries for own (e, 4 rows): h_h + h_v */            \
        if ((S) + 1 < NCELL) {                                              \
            const float hh_ = (jn_ == 0) ? 0.f : 1.f;                       \
            const float v0 = hh_*h0 + ((cn_==c_) ? h0 : (float)hvp[0]);     \
            const float v1 = hh_*h1 + ((cn_==c_) ? h1 : (float)hvp[1]);     \
            const float v2 = hh_*h2 + ((cn_==c_) ? h2 : (float)hvp[2]);     \
            const float v3 = hh_*h3 + ((cn_==c_) ? h3 : (float)hvp[3]);     \
            f16x4 vp; vp[0]=(f16)v0; vp[1]=(f16)v1; vp[2]=(f16)v2; vp[3]=(f16)v3; \
            *(f16x4*)&inpL[(Q) ^ 1][e * 136 + kq] = vp;                     \
        }                                                                   \
        f16x4 hp; hp[0]=(f16)h0; hp[1]=(f16)h1; hp[2]=(f16)h2; hp[3]=(f16)h3; \
        *(f16x4*)&hvl[t * 132 + c_ * 4] = hp;                               \
        bar_lds();   /* single barrier: publishes X, fp_ */                 \
    }

    // prologue: weights for cells 0 and 1 in flight
    ISSUE(0, A0,A1,A2,A3, AT0,AT1);
    ISSUE(1, B0,B1,B2,B3, BT0,BT1);

    for (int s = 0; s < NCELL; s += 4) {
        ISSUE(s + 2, C0,C1,C2,C3, CT0,CT1); WAITP();
        PROC(s,     0, A0,A1,A2,A3, AT0,AT1);
        ISSUE(s + 3, D0,D1,D2,D3, DT0,DT1); WAITP();
        PROC(s + 1, 1, B0,B1,B2,B3, BT0,BT1);
        ISSUE(s + 4, A0,A1,A2,A3, AT0,AT1); WAITP();
        PROC(s + 2, 0, C0,C1,C2,C3, CT0,CT1);
        ISSUE(s + 5, B0,B1,B2,B3, BT0,BT1); WAITP();
        PROC(s + 3, 1, D0,D1,D2,D3, DT0,DT1);
    }
#undef ISSUE
#undef WAITP
#undef PROC

    // tail: lp for cell 1023 (its fp_ landed in parity 0; final barrier ran)
    if (w == 0 && l < 32) {
        const int hf = l >> 4;
        const int cp = cell_of(NCELL - 1);
        const float4 fa = *(const float4*)&fp_[0][e][0];
        const float4 fb = *(const float4*)&fp_[0][e][4];
        const float z = ((fa.x + fa.y) + (fa.z + fa.w))
                      + ((fb.x + fb.y) + (fb.z + fb.w)) + bfs[cp];
        const float xh = 1.f / (1.f + __expf(-z));
        const float m = (float)((smpw[cp] >> e) & 1);
        lp += (hf == 0) ? __logf(xh + NEPS) * m
                        : __logf(1.f - xh + NEPS) * (1.f - m);
        const float lpo = lp + __shfl_down(lp, 16);
        if (hf == 0) out[b0 + e] = lpo;
    }
}

extern "C" void kernel_launch(void* const* d_in, const int* in_sizes, int n_in,
                              void* d_out, int out_size, void* d_ws, size_t ws_size,
                              hipStream_t stream) {
    const float* samples = (const float*)d_in[0];
    const float* W1      = (const float*)d_in[1];
    const float* b1      = (const float*)d_in[2];
    const float* Wf      = (const float*)d_in[3];
    const float* bf      = (const float*)d_in[4];
    float* outp = (float*)d_out;
    char* Wt = (char*)d_ws;   // 1024 * 33792 B = 34.6 MB

    transpose_w<<<1024, 256, 0, stream>>>(W1, b1, Wf, Wt);
    rnn2d<<<512 / ELEMS, 512, 0, stream>>>(samples, Wt, bf, outp);
}